// Round 11
// baseline (100.933 us; speedup 1.0000x reference)
//
#include <hip/hip_runtime.h>
#include <hip/hip_bf16.h>
#include <math.h>

#define N_PTS  131072
#define K_DIM  16
#define D_BINS 1024
// packed-screen commit margin (10-bit index packing): truncation to 13
// mantissa bits (2^-12=2.44e-4 for scores in [2,4)) + screen err (~1.3e-5
// incl. split-acc reorder ~1e-7) + headroom => 3.5e-4.  (proven R7/R9/R10)
#define MARGIN_P 3.5e-4f

typedef short bf16x8 __attribute__((ext_vector_type(8)));
typedef float f32x4  __attribute__((ext_vector_type(4)));

// ws layout (bytes):
// [64,+64K) bnT rows | [65600,+32K) B1 | [98368,+32K) B2  (B1||B2 contiguous)
#define WS_OFF_BN  64
#define WS_OFF_B1  65600
#define WS_OFF_B2  98368
#define WS_NEED    131136

// np-exact normalization over K (sequential ascending k, no fma).
__device__ __forceinline__ void norm_np(const float* __restrict__ p,
                                        int stride, int n, float* __restrict__ a) {
#pragma clang fp contract(off)
    float v[K_DIM];
#pragma unroll
    for (int k = 0; k < K_DIM; ++k) v[k] = p[(size_t)k * stride + n];
    float s = v[0];
#pragma unroll
    for (int k = 1; k < K_DIM; ++k) s = s + v[k];
    const float mean = s / 16.0f;
    float sq[K_DIM];
#pragma unroll
    for (int k = 0; k < K_DIM; ++k) { a[k] = v[k] - mean; sq[k] = a[k] * a[k]; }
    float ss = sq[0];
#pragma unroll
    for (int k = 1; k < K_DIM; ++k) ss = ss + sq[k];
    const float denom = sqrtf(ss) + 1e-10f;
#pragma unroll
    for (int k = 0; k < K_DIM; ++k) a[k] = a[k] / denom;
}

__device__ __forceinline__ unsigned short bf16_bits(float f) {
    __hip_bfloat16 h = __float2bfloat16(f);   // RNE
    unsigned short u;
    __builtin_memcpy(&u, &h, 2);
    return u;
}
__device__ __forceinline__ float bf16_val(float f) {
    return __bfloat162float(__float2bfloat16(f));
}

// med3(ub1, ub2, u) == max(ub2, min(ub1, u)) given invariant ub1 >= ub2
// (proven correct in the R2/R4-R10 passing runs)
__device__ __forceinline__ unsigned v_med3u(unsigned a, unsigned b, unsigned c) {
    unsigned d;
    asm("v_med3_u32 %0, %1, %2, %3" : "=v"(d) : "v"(a), "v"(b), "v"(c));
    return d;
}

// Kernel 1: np-exact cmat normalize -> bnT rows + hi/lo MFMA B-fragments
// (16x16x32 layout verified across R0/R2/R4-R10).
__global__ __launch_bounds__(256) void prep_b(
    const float* __restrict__ cmat, float* __restrict__ bnT,
    unsigned short* __restrict__ B1, unsigned short* __restrict__ B2) {
#pragma clang fp contract(off)
    const int d = blockIdx.x * 256 + threadIdx.x;   // grid = 4 * 256
    if (d >= D_BINS) return;

    float t[K_DIM];
    norm_np(cmat, D_BINS, d, t);

    const int tile = d >> 4, n = d & 15;
#pragma unroll
    for (int k = 0; k < K_DIM; ++k) {
        bnT[d * K_DIM + k] = t[k];
        const float hi_f = bf16_val(t[k]);
        const int idx = tile * 256 + ((k >> 3) * 16 + n) * 8 + (k & 7);
        B1[idx] = bf16_bits(t[k]);
        B2[idx] = bf16_bits(t[k] - hi_f);
    }
}

// Kernel 2: MFMA screen — R10 structure (B1+B2 in 64 KB LDS, 10-bit pack,
// pooled rescan) with SPLIT INDEPENDENT ACCUMULATORS:
//   acc1 = mfma(A,  b1, {2})    // (Ahi+Alo)*B1
//   acc2 = mfma(A2, b2, {0})    // Ahi*B2   (independent -> no serial chain)
//   score = acc1[r] + acc2[r]   // fp32 add; reorder err ~1e-7 << margin
// Top-2 packed uint (score&~0x3FF)|(1023-d): and_or + v_max + v_med3.
__global__ __launch_bounds__(512, 4) void mfma_screen(
    const float* __restrict__ x, const uint4* __restrict__ Bfrag,
    const float* __restrict__ bnT, int* __restrict__ out) {
#pragma clang fp contract(off)
    __shared__ uint4 ldsB[4096];     // [0,2048)=B1, [2048,4096)=B2  (64 KB)

    {
#pragma unroll
        for (int j = 0; j < 8; ++j)
            ldsB[threadIdx.x + j * 512] = Bfrag[threadIdx.x + j * 512];
    }

    const int lane = threadIdx.x & 63;
    const int wv   = threadIdx.x >> 6;              // 0..7
    const int W    = blockIdx.x * 8 + wv;           // grid = 1024 * 512
    const int P    = W * 16;
    const int m    = lane & 15;                     // bin column within tile
    const int q    = lane >> 4;                     // quad

    // A fragment (16 points): kp=(lane>>4)*8+j; kp<16 -> hi, kp>=16 -> lo.
    // A2: hi for kp<16, zero for kp>=16 (feeds the B2 mfma).
    bf16x8 A, A2;
    {
        float a[K_DIM];
        norm_np(x, N_PTS, P + m, a);
        unsigned short els[8];
#pragma unroll
        for (int j = 0; j < 8; ++j) {
            const int k = (q & 1) * 8 + j;
            if (q < 2) els[j] = bf16_bits(a[k]);
            else       els[j] = bf16_bits(a[k] - bf16_val(a[k]));
        }
        __builtin_memcpy(&A, els, 16);
        A2 = (q < 2) ? A : (bf16x8)(short)0;
    }

    __syncthreads();

    // Both halves from LDS, lanes mirrored (L and L+32 same address -> bcast).
    const uint4* b1p = ldsB + (lane & 31);
    const uint4* b2p = ldsB + 2048 + (lane & 31);

    unsigned ub1[4], ub2[4];
#pragma unroll
    for (int r = 0; r < 4; ++r) { ub1[r] = 0u; ub2[r] = 0u; }

    const unsigned mask  = 0xFFFFFC00u;             // 10-bit index packing
    const unsigned dbase = 1023u - (unsigned)m;

#pragma unroll 4
    for (int i = 0; i < 64; ++i) {
        const uint4 w1 = b1p[i * 32];
        const uint4 w2 = b2p[i * 32];
        const bf16x8 bf1 = __builtin_bit_cast(bf16x8, w1);
        const bf16x8 bf2 = __builtin_bit_cast(bf16x8, w2);

        const f32x4 acc1 = __builtin_amdgcn_mfma_f32_16x16x32_bf16(
            A, bf1, (f32x4){2.f, 2.f, 2.f, 2.f}, 0, 0, 0);
        const f32x4 acc2 = __builtin_amdgcn_mfma_f32_16x16x32_bf16(
            A2, bf2, (f32x4){0.f, 0.f, 0.f, 0.f}, 0, 0, 0);

        const unsigned dcomp = dbase - (unsigned)(i * 16);
#pragma unroll
        for (int r = 0; r < 4; ++r) {
            const float sc     = acc1[r] + acc2[r];
            const unsigned u   = (__float_as_uint(sc) & mask) | dcomp;
            const unsigned nb2 = v_med3u(ub1[r], ub2[r], u);
            ub1[r] = max(ub1[r], u);
            ub2[r] = nb2;
        }
    }

    // merge top-2 across the 16 bin-columns (m) of each quad group; collect
    // margin failures into a wave-uniform bitmap (bit = q*4 + r).
    unsigned fail16 = 0;
#pragma unroll
    for (int r = 0; r < 4; ++r) {
        unsigned u1 = ub1[r], u2 = ub2[r];
#pragma unroll
        for (int s = 1; s <= 8; s <<= 1) {
            const unsigned o1 = (unsigned)__shfl_xor((int)u1, s, 16);
            const unsigned o2 = (unsigned)__shfl_xor((int)u2, s, 16);
            const unsigned n1 = max(u1, o1);
            u2 = max(min(u1, o1), max(u2, o2));
            u1 = n1;
        }
        int fail = 0;
        if (m == 0) {
            const int p  = P + q * 4 + r;
            const float s1 = __uint_as_float(u1 & mask);
            const float s2 = __uint_as_float(u2 & mask);
            if (s1 - s2 > MARGIN_P) out[p] = 1023 - (int)(u1 & 1023u);
            else fail = 1;
        }
        const unsigned long long bm = __ballot(fail);  // set lanes in {0,16,32,48}
        fail16 |= (unsigned)((bm      ) & 1ull) << (r);
        fail16 |= (unsigned)((bm >> 16) & 1ull) << (4 + r);
        fail16 |= (unsigned)((bm >> 32) & 1ull) << (8 + r);
        fail16 |= (unsigned)((bm >> 48) & 1ull) << (12 + r);
    }

    // ---- block-pooled rescan (proven R5-R10) ----
    // All waves are done reading ldsB after this barrier; reuse its first
    // bytes as {counter, list[<=128]} of failing point ids.
    __syncthreads();
    int* pool = reinterpret_cast<int*>(ldsB);
    if (threadIdx.x == 0) pool[0] = 0;
    __syncthreads();
    if (lane == 0) {
        unsigned f = fail16;
        while (f) {
            const int s = __builtin_ffs((int)f) - 1;
            f &= f - 1;
            const int pos = atomicAdd(pool, 1);
            pool[1 + pos] = P + s;
        }
    }
    __syncthreads();
    const int cnt = pool[0];

    // waves process the block's failures round-robin (verbatim proven
    // 64-lane np-exact rescan per point; unroll-4 interleaves the
    // independent dependent-add chains; per-bin summation order unchanged).
    for (int j = wv; j < cnt; j += 8) {
        const int p = pool[1 + j];

        float a[K_DIM];
        norm_np(x, N_PTS, p, a);

        float best = -3.402823466e38f;
        int   idx  = 0x7fffffff;
        const float4* b4 = (const float4*)bnT;
#pragma unroll 4
        for (int t = 0; t < 16; ++t) {
            const int d = t * 64 + lane;
            const float4 q0 = b4[d * 4 + 0];
            const float4 q1 = b4[d * 4 + 1];
            const float4 q2 = b4[d * 4 + 2];
            const float4 q3 = b4[d * 4 + 3];
            float sc;
            sc = a[0] * q0.x;
            sc = sc + a[1]  * q0.y; sc = sc + a[2]  * q0.z; sc = sc + a[3]  * q0.w;
            sc = sc + a[4]  * q1.x; sc = sc + a[5]  * q1.y; sc = sc + a[6]  * q1.z;
            sc = sc + a[7]  * q1.w; sc = sc + a[8]  * q2.x; sc = sc + a[9]  * q2.y;
            sc = sc + a[10] * q2.z; sc = sc + a[11] * q2.w; sc = sc + a[12] * q3.x;
            sc = sc + a[13] * q3.y; sc = sc + a[14] * q3.z; sc = sc + a[15] * q3.w;
            if (sc > best) { best = sc; idx = d; }
        }
#pragma unroll
        for (int mk = 1; mk <= 32; mk <<= 1) {
            const float ob = __shfl_xor(best, mk);
            const int   oi = __shfl_xor(idx,  mk);
            if (ob > best || (ob == best && oi < idx)) { best = ob; idx = oi; }
        }
        if (lane == 0) out[p] = idx;
    }
}

// Fallback (small ws): proven-exact full scan (R4).
__global__ __launch_bounds__(256) void ncc_argmax_np32(
    const float* __restrict__ x, const float* __restrict__ bnT,
    int* __restrict__ out) {
#pragma clang fp contract(off)
    const int n = blockIdx.x * 256 + threadIdx.x;
    float a[K_DIM];
    norm_np(x, N_PTS, n, a);

    float best = -3.402823466e38f;
    int   idx  = 0;
    const float4* b4 = (const float4*)bnT;
#pragma unroll 2
    for (int d = 0; d < D_BINS; ++d) {
        const float4 q0 = b4[d * 4 + 0];
        const float4 q1 = b4[d * 4 + 1];
        const float4 q2 = b4[d * 4 + 2];
        const float4 q3 = b4[d * 4 + 3];
        float sc;
        sc = a[0] * q0.x;
        sc = sc + a[1]  * q0.y; sc = sc + a[2]  * q0.z; sc = sc + a[3]  * q0.w;
        sc = sc + a[4]  * q1.x; sc = sc + a[5]  * q1.y; sc = sc + a[6]  * q1.z;
        sc = sc + a[7]  * q1.w; sc = sc + a[8]  * q2.x; sc = sc + a[9]  * q2.y;
        sc = sc + a[10] * q2.z; sc = sc + a[11] * q2.w; sc = sc + a[12] * q3.x;
        sc = sc + a[13] * q3.y; sc = sc + a[14] * q3.z; sc = sc + a[15] * q3.w;
        if (sc > best) { best = sc; idx = d; }
    }
    out[n] = idx;
}

__global__ __launch_bounds__(256) void normalize_rows_only(
    const float* __restrict__ cmat, float* __restrict__ bnT) {
#pragma clang fp contract(off)
    const int d = blockIdx.x * 256 + threadIdx.x;
    if (d >= D_BINS) return;
    float t[K_DIM];
    norm_np(cmat, D_BINS, d, t);
#pragma unroll
    for (int k = 0; k < K_DIM; ++k) bnT[d * K_DIM + k] = t[k];
}

extern "C" void kernel_launch(void* const* d_in, const int* in_sizes, int n_in,
                              void* d_out, int out_size, void* d_ws, size_t ws_size,
                              hipStream_t stream) {
    const float* x    = (const float*)d_in[0];   // [1, 16, 131072] fp32
    const float* cmat = (const float*)d_in[1];   // [16, 1024] fp32
    int* out = (int*)d_out;                      // [1, 131072] int32
    char* ws = (char*)d_ws;

    if (ws_size >= (size_t)WS_NEED) {
        float*          bnT = (float*)(ws + WS_OFF_BN);
        unsigned short* B1  = (unsigned short*)(ws + WS_OFF_B1);
        unsigned short* B2  = (unsigned short*)(ws + WS_OFF_B2);

        prep_b<<<4, 256, 0, stream>>>(cmat, bnT, B1, B2);
        mfma_screen<<<1024, 512, 0, stream>>>(
            x, (const uint4*)(ws + WS_OFF_B1), bnT, out);
    } else {
        float* bnT = (float*)(ws + WS_OFF_BN);
        normalize_rows_only<<<4, 256, 0, stream>>>(cmat, bnT);
        ncc_argmax_np32<<<512, 256, 0, stream>>>(x, bnT, out);
    }
}

// Round 12
// 97.511 us; speedup vs baseline: 1.0351x; 1.0351x over previous
//
#include <hip/hip_runtime.h>
#include <hip/hip_bf16.h>
#include <math.h>

#define N_PTS  131072
#define K_DIM  16
#define D_BINS 1024
// packed-screen commit margin (10-bit index packing): truncation to 13
// mantissa bits (2^-12=2.44e-4 for scores in [2,4)) + screen err (~1.3e-5)
// + headroom => 3.5e-4.  (proven R7/R9/R10)
#define MARGIN_P 3.5e-4f

typedef short bf16x8 __attribute__((ext_vector_type(8)));
typedef float f32x4  __attribute__((ext_vector_type(4)));

// ws layout (bytes):
// [64,+64K) bnT rows | [65600,+32K) B1 | [98368,+32K) B2  (B1||B2 contiguous)
#define WS_OFF_BN  64
#define WS_OFF_B1  65600
#define WS_OFF_B2  98368
#define WS_NEED    131136

// np-exact normalization over K (sequential ascending k, no fma).
__device__ __forceinline__ void norm_np(const float* __restrict__ p,
                                        int stride, int n, float* __restrict__ a) {
#pragma clang fp contract(off)
    float v[K_DIM];
#pragma unroll
    for (int k = 0; k < K_DIM; ++k) v[k] = p[(size_t)k * stride + n];
    float s = v[0];
#pragma unroll
    for (int k = 1; k < K_DIM; ++k) s = s + v[k];
    const float mean = s / 16.0f;
    float sq[K_DIM];
#pragma unroll
    for (int k = 0; k < K_DIM; ++k) { a[k] = v[k] - mean; sq[k] = a[k] * a[k]; }
    float ss = sq[0];
#pragma unroll
    for (int k = 1; k < K_DIM; ++k) ss = ss + sq[k];
    const float denom = sqrtf(ss) + 1e-10f;
#pragma unroll
    for (int k = 0; k < K_DIM; ++k) a[k] = a[k] / denom;
}

__device__ __forceinline__ unsigned short bf16_bits(float f) {
    __hip_bfloat16 h = __float2bfloat16(f);   // RNE
    unsigned short u;
    __builtin_memcpy(&u, &h, 2);
    return u;
}
__device__ __forceinline__ float bf16_val(float f) {
    return __bfloat162float(__float2bfloat16(f));
}

// med3(ub1, ub2, u) == max(ub2, min(ub1, u)) given invariant ub1 >= ub2
// (proven correct in the R2/R4-R10 passing runs)
__device__ __forceinline__ unsigned v_med3u(unsigned a, unsigned b, unsigned c) {
    unsigned d;
    asm("v_med3_u32 %0, %1, %2, %3" : "=v"(d) : "v"(a), "v"(b), "v"(c));
    return d;
}

// Kernel 1: np-exact cmat normalize -> bnT rows + hi/lo MFMA B-fragments
// (16x16x32 layout verified across R0/R2/R4-R10).
__global__ __launch_bounds__(256) void prep_b(
    const float* __restrict__ cmat, float* __restrict__ bnT,
    unsigned short* __restrict__ B1, unsigned short* __restrict__ B2) {
#pragma clang fp contract(off)
    const int d = blockIdx.x * 256 + threadIdx.x;   // grid = 4 * 256
    if (d >= D_BINS) return;

    float t[K_DIM];
    norm_np(cmat, D_BINS, d, t);

    const int tile = d >> 4, n = d & 15;
#pragma unroll
    for (int k = 0; k < K_DIM; ++k) {
        bnT[d * K_DIM + k] = t[k];
        const float hi_f = bf16_val(t[k]);
        const int idx = tile * 256 + ((k >> 3) * 16 + n) * 8 + (k & 7);
        B1[idx] = bf16_bits(t[k]);
        B2[idx] = bf16_bits(t[k] - hi_f);
    }
}

// Kernel 2: MFMA screen — R5's main-loop config (B1+B2 both in 64 KB LDS,
// the best-measured main loop: 40.8 µs) + R7's tail (10-bit packing,
// margin 3.5e-4, unroll-4 block-pooled rescan: ~4.5 µs).  [R10 = session best]
// Per bin-tile:
//   acc = mfma(A,  b1, C=2.0)   // (Ahi+Alo)*B1hi   (b1 bcast to both halves)
//   acc = mfma(A2, b2, acc)     // Ahi*B2lo; A2 zero for quads>=2
// Top-2 packed uint (score&~0x3FF)|(1023-d): and_or + v_max + v_med3.
__global__ __launch_bounds__(512, 4) void mfma_screen(
    const float* __restrict__ x, const uint4* __restrict__ Bfrag,
    const float* __restrict__ bnT, int* __restrict__ out) {
#pragma clang fp contract(off)
    __shared__ uint4 ldsB[4096];     // [0,2048)=B1, [2048,4096)=B2  (64 KB)

    {
#pragma unroll
        for (int j = 0; j < 8; ++j)
            ldsB[threadIdx.x + j * 512] = Bfrag[threadIdx.x + j * 512];
    }

    const int lane = threadIdx.x & 63;
    const int wv   = threadIdx.x >> 6;              // 0..7
    const int W    = blockIdx.x * 8 + wv;           // grid = 1024 * 512
    const int P    = W * 16;
    const int m    = lane & 15;                     // bin column within tile
    const int q    = lane >> 4;                     // quad

    // A fragment (16 points): kp=(lane>>4)*8+j; kp<16 -> hi, kp>=16 -> lo.
    // A2: hi for kp<16, zero for kp>=16 (feeds the B2 mfma).
    bf16x8 A, A2;
    {
        float a[K_DIM];
        norm_np(x, N_PTS, P + m, a);
        unsigned short els[8];
#pragma unroll
        for (int j = 0; j < 8; ++j) {
            const int k = (q & 1) * 8 + j;
            if (q < 2) els[j] = bf16_bits(a[k]);
            else       els[j] = bf16_bits(a[k] - bf16_val(a[k]));
        }
        __builtin_memcpy(&A, els, 16);
        A2 = (q < 2) ? A : (bf16x8)(short)0;
    }

    __syncthreads();

    // Both halves from LDS, lanes mirrored (L and L+32 same address -> bcast).
    const uint4* b1p = ldsB + (lane & 31);
    const uint4* b2p = ldsB + 2048 + (lane & 31);

    unsigned ub1[4], ub2[4];
#pragma unroll
    for (int r = 0; r < 4; ++r) { ub1[r] = 0u; ub2[r] = 0u; }

    const unsigned mask  = 0xFFFFFC00u;             // 10-bit index packing
    const unsigned dbase = 1023u - (unsigned)m;

#pragma unroll 4
    for (int i = 0; i < 64; ++i) {
        const uint4 w1 = b1p[i * 32];
        const uint4 w2 = b2p[i * 32];
        const bf16x8 bf1 = __builtin_bit_cast(bf16x8, w1);
        const bf16x8 bf2 = __builtin_bit_cast(bf16x8, w2);

        f32x4 acc = __builtin_amdgcn_mfma_f32_16x16x32_bf16(
            A, bf1, (f32x4){2.f, 2.f, 2.f, 2.f}, 0, 0, 0);
        acc = __builtin_amdgcn_mfma_f32_16x16x32_bf16(A2, bf2, acc, 0, 0, 0);

        const unsigned dcomp = dbase - (unsigned)(i * 16);
#pragma unroll
        for (int r = 0; r < 4; ++r) {
            const unsigned u   = (__float_as_uint(acc[r]) & mask) | dcomp;
            const unsigned nb2 = v_med3u(ub1[r], ub2[r], u);
            ub1[r] = max(ub1[r], u);
            ub2[r] = nb2;
        }
    }

    // merge top-2 across the 16 bin-columns (m) of each quad group; collect
    // margin failures into a wave-uniform bitmap (bit = q*4 + r).
    unsigned fail16 = 0;
#pragma unroll
    for (int r = 0; r < 4; ++r) {
        unsigned u1 = ub1[r], u2 = ub2[r];
#pragma unroll
        for (int s = 1; s <= 8; s <<= 1) {
            const unsigned o1 = (unsigned)__shfl_xor((int)u1, s, 16);
            const unsigned o2 = (unsigned)__shfl_xor((int)u2, s, 16);
            const unsigned n1 = max(u1, o1);
            u2 = max(min(u1, o1), max(u2, o2));
            u1 = n1;
        }
        int fail = 0;
        if (m == 0) {
            const int p  = P + q * 4 + r;
            const float s1 = __uint_as_float(u1 & mask);
            const float s2 = __uint_as_float(u2 & mask);
            if (s1 - s2 > MARGIN_P) out[p] = 1023 - (int)(u1 & 1023u);
            else fail = 1;
        }
        const unsigned long long bm = __ballot(fail);  // set lanes in {0,16,32,48}
        fail16 |= (unsigned)((bm      ) & 1ull) << (r);
        fail16 |= (unsigned)((bm >> 16) & 1ull) << (4 + r);
        fail16 |= (unsigned)((bm >> 32) & 1ull) << (8 + r);
        fail16 |= (unsigned)((bm >> 48) & 1ull) << (12 + r);
    }

    // ---- block-pooled rescan (proven R5-R10) ----
    // All waves are done reading ldsB after this barrier; reuse its first
    // bytes as {counter, list[<=128]} of failing point ids.
    __syncthreads();
    int* pool = reinterpret_cast<int*>(ldsB);
    if (threadIdx.x == 0) pool[0] = 0;
    __syncthreads();
    if (lane == 0) {
        unsigned f = fail16;
        while (f) {
            const int s = __builtin_ffs((int)f) - 1;
            f &= f - 1;
            const int pos = atomicAdd(pool, 1);
            pool[1 + pos] = P + s;
        }
    }
    __syncthreads();
    const int cnt = pool[0];

    // waves process the block's failures round-robin (verbatim proven
    // 64-lane np-exact rescan per point; unroll-4 interleaves the
    // independent dependent-add chains; per-bin summation order unchanged).
    for (int j = wv; j < cnt; j += 8) {
        const int p = pool[1 + j];

        float a[K_DIM];
        norm_np(x, N_PTS, p, a);

        float best = -3.402823466e38f;
        int   idx  = 0x7fffffff;
        const float4* b4 = (const float4*)bnT;
#pragma unroll 4
        for (int t = 0; t < 16; ++t) {
            const int d = t * 64 + lane;
            const float4 q0 = b4[d * 4 + 0];
            const float4 q1 = b4[d * 4 + 1];
            const float4 q2 = b4[d * 4 + 2];
            const float4 q3 = b4[d * 4 + 3];
            float sc;
            sc = a[0] * q0.x;
            sc = sc + a[1]  * q0.y; sc = sc + a[2]  * q0.z; sc = sc + a[3]  * q0.w;
            sc = sc + a[4]  * q1.x; sc = sc + a[5]  * q1.y; sc = sc + a[6]  * q1.z;
            sc = sc + a[7]  * q1.w; sc = sc + a[8]  * q2.x; sc = sc + a[9]  * q2.y;
            sc = sc + a[10] * q2.z; sc = sc + a[11] * q2.w; sc = sc + a[12] * q3.x;
            sc = sc + a[13] * q3.y; sc = sc + a[14] * q3.z; sc = sc + a[15] * q3.w;
            if (sc > best) { best = sc; idx = d; }
        }
#pragma unroll
        for (int mk = 1; mk <= 32; mk <<= 1) {
            const float ob = __shfl_xor(best, mk);
            const int   oi = __shfl_xor(idx,  mk);
            if (ob > best || (ob == best && oi < idx)) { best = ob; idx = oi; }
        }
        if (lane == 0) out[p] = idx;
    }
}

// Fallback (small ws): proven-exact full scan (R4).
__global__ __launch_bounds__(256) void ncc_argmax_np32(
    const float* __restrict__ x, const float* __restrict__ bnT,
    int* __restrict__ out) {
#pragma clang fp contract(off)
    const int n = blockIdx.x * 256 + threadIdx.x;
    float a[K_DIM];
    norm_np(x, N_PTS, n, a);

    float best = -3.402823466e38f;
    int   idx  = 0;
    const float4* b4 = (const float4*)bnT;
#pragma unroll 2
    for (int d = 0; d < D_BINS; ++d) {
        const float4 q0 = b4[d * 4 + 0];
        const float4 q1 = b4[d * 4 + 1];
        const float4 q2 = b4[d * 4 + 2];
        const float4 q3 = b4[d * 4 + 3];
        float sc;
        sc = a[0] * q0.x;
        sc = sc + a[1]  * q0.y; sc = sc + a[2]  * q0.z; sc = sc + a[3]  * q0.w;
        sc = sc + a[4]  * q1.x; sc = sc + a[5]  * q1.y; sc = sc + a[6]  * q1.z;
        sc = sc + a[7]  * q1.w; sc = sc + a[8]  * q2.x; sc = sc + a[9]  * q2.y;
        sc = sc + a[10] * q2.z; sc = sc + a[11] * q2.w; sc = sc + a[12] * q3.x;
        sc = sc + a[13] * q3.y; sc = sc + a[14] * q3.z; sc = sc + a[15] * q3.w;
        if (sc > best) { best = sc; idx = d; }
    }
    out[n] = idx;
}

__global__ __launch_bounds__(256) void normalize_rows_only(
    const float* __restrict__ cmat, float* __restrict__ bnT) {
#pragma clang fp contract(off)
    const int d = blockIdx.x * 256 + threadIdx.x;
    if (d >= D_BINS) return;
    float t[K_DIM];
    norm_np(cmat, D_BINS, d, t);
#pragma unroll
    for (int k = 0; k < K_DIM; ++k) bnT[d * K_DIM + k] = t[k];
}

extern "C" void kernel_launch(void* const* d_in, const int* in_sizes, int n_in,
                              void* d_out, int out_size, void* d_ws, size_t ws_size,
                              hipStream_t stream) {
    const float* x    = (const float*)d_in[0];   // [1, 16, 131072] fp32
    const float* cmat = (const float*)d_in[1];   // [16, 1024] fp32
    int* out = (int*)d_out;                      // [1, 131072] int32
    char* ws = (char*)d_ws;

    if (ws_size >= (size_t)WS_NEED) {
        float*          bnT = (float*)(ws + WS_OFF_BN);
        unsigned short* B1  = (unsigned short*)(ws + WS_OFF_B1);
        unsigned short* B2  = (unsigned short*)(ws + WS_OFF_B2);

        prep_b<<<4, 256, 0, stream>>>(cmat, bnT, B1, B2);
        mfma_screen<<<1024, 512, 0, stream>>>(
            x, (const uint4*)(ws + WS_OFF_B1), bnT, out);
    } else {
        float* bnT = (float*)(ws + WS_OFF_BN);
        normalize_rows_only<<<4, 256, 0, stream>>>(cmat, bnT);
        ncc_argmax_np32<<<512, 256, 0, stream>>>(x, bnT, out);
    }
}